// Round 1
// baseline (544.006 us; speedup 1.0000x reference)
//
#include <hip/hip_runtime.h>
#include <math.h>

typedef unsigned short u16;
typedef unsigned int u32;
typedef _Float16 f16;
typedef __attribute__((ext_vector_type(8))) _Float16 f16x8;   // MFMA A/B frag
typedef __attribute__((ext_vector_type(4))) float f32x4;      // MFMA acc

static constexpr int B_   = 32;
static constexpr int C_   = 2048;
static constexpr int N_   = 576;    // H*W
static constexpr int MID_ = 256;
static constexpr int M_   = 512;    // 2*MID
static constexpr int NB_  = B_ * N_;  // 18432 = 144*128

// global -> LDS direct DMA, 16 B per lane (wave-uniform LDS base + lane*16)
typedef const __attribute__((address_space(1))) unsigned int gu32_t;
typedef __attribute__((address_space(3))) unsigned int lu32_t;
__device__ __forceinline__ void gl16(const void* g, void* l) {
  __builtin_amdgcn_global_load_lds((gu32_t*)g, (lu32_t*)l, 16, 0, 0);
}

// LDS swizzle (rule #21: linear DMA dest + pre-swizzled global SOURCE + swizzled READ):
//   LDS tile row = 64 B = 4 slots of 16 B. slot s of row r holds global chunk
//   s ^ ((r>>1)&3). Staging lane l (dest = base + l*16) must therefore fetch
//   global chunk (l&3) ^ ((l>>3)&3) of row r0 + (l>>2).
//   Read of chunk g of row r is at slot g ^ ((r>>1)&3). For fragment reads
//   (r = wm + 16*i + fr, wm/16i have no bits 1..2) this is lane-constant:
//   qo = ((lane>>4) ^ ((lane>>1)&3)) * 8.
//   Spreads the former 8-way ds_read_b128 conflict to 2-way (free, m136).

// ---------------------------------------------------------------------------
// Prep W: Wcat = [W1;W2] (512x2048) -> fp16, k-contiguous.
// ---------------------------------------------------------------------------
__global__ __launch_bounds__(256) void k_prep_w(
    const float* __restrict__ W1, const float* __restrict__ W2,
    f16* __restrict__ Wc) {
  const int e0 = (blockIdx.x * 256 + threadIdx.x) * 8;
  const int m = e0 >> 11;
  const int c = e0 & 2047;
  const float* src = (m < MID_) ? &W1[(size_t)m * C_ + c]
                                : &W2[(size_t)(m - MID_) * C_ + c];
  const float4 a = *(const float4*)&src[0];
  const float4 b = *(const float4*)&src[4];
  f16x8 hv;
  hv[0] = (f16)a.x; hv[1] = (f16)a.y; hv[2] = (f16)a.z; hv[3] = (f16)a.w;
  hv[4] = (f16)b.x; hv[5] = (f16)b.y; hv[6] = (f16)b.z; hv[7] = (f16)b.w;
  *(f16x8*)&Wc[e0] = hv;
}

// ---------------------------------------------------------------------------
// Prep feat: feat[b][c][n] fp32 -> fT[(b*576+n)][c] fp16 (transpose).
// 64x64 tile via LDS; grid (32 ctiles, 9 ntiles, 32 b).
// ---------------------------------------------------------------------------
__global__ __launch_bounds__(256) void k_prep_feat(
    const float* __restrict__ feat, f16* __restrict__ fT) {
  const int c0 = blockIdx.x * 64;
  const int n0 = blockIdx.y * 64;
  const int b  = blockIdx.z;
  __shared__ float Ts[64][65];
  const float* src = feat + ((size_t)b * C_ + c0) * N_ + n0;
  const int t = threadIdx.x;
  const int tr  = t >> 4;
  const int tc4 = (t & 15) * 4;
#pragma unroll
  for (int e = 0; e < 4; ++e) {
    const int c = tr + e * 16;
    const float4 v = *(const float4*)&src[(size_t)c * N_ + tc4];
    Ts[c][tc4] = v.x; Ts[c][tc4 + 1] = v.y;
    Ts[c][tc4 + 2] = v.z; Ts[c][tc4 + 3] = v.w;
  }
  __syncthreads();
  const int co = (t & 7) * 8;
#pragma unroll
  for (int p = 0; p < 2; ++p) {
    const int n = (t >> 3) + p * 32;
    f16x8 hv;
#pragma unroll
    for (int e = 0; e < 8; ++e) hv[e] = (f16)Ts[co + e][n];
    *(f16x8*)&fT[((size_t)b * N_ + n0 + n) * C_ + c0 + co] = hv;
  }
}

// ---------------------------------------------------------------------------
// Prep cam: fp32 -> fp16 (layout unchanged; k=j contiguous).
// ---------------------------------------------------------------------------
__global__ __launch_bounds__(256) void k_prep_cam(
    const float* __restrict__ cam, f16* __restrict__ camh) {
  const int e0 = (blockIdx.x * 256 + threadIdx.x) * 8;
  const float4 a = *(const float4*)&cam[e0];
  const float4 b = *(const float4*)&cam[e0 + 4];
  f16x8 hv;
  hv[0] = (f16)a.x; hv[1] = (f16)a.y; hv[2] = (f16)a.z; hv[3] = (f16)a.w;
  hv[4] = (f16)b.x; hv[5] = (f16)b.y; hv[6] = (f16)b.z; hv[7] = (f16)b.w;
  *(f16x8*)&camh[e0] = hv;
}

// ---------------------------------------------------------------------------
// K1: f12[(b n)][m] = sum_c fT[(b n)][c] * Wcat[m][c]  — one flat GEMM,
// M=512, N=18432, K=2048. 128x128 tile, BK=32, fp16 MFMA.
// 2-phase prefetch double-buffer + XOR swizzle. Grid (4 mtiles, 144 ntiles).
// ---------------------------------------------------------------------------
__global__ __launch_bounds__(256) void k_f12(
    const f16* __restrict__ fT, const f16* __restrict__ Wc,
    f16* __restrict__ f12) {
  const int mt = blockIdx.x;  // 0..3
  const int nt = blockIdx.y;  // 0..143
  __shared__ __align__(16) f16 As[2][128 * 32], Bs[2][128 * 32];
  const int t = threadIdx.x, lane = t & 63, w = t >> 6;
  const int wm = (w >> 1) * 64, wn = (w & 1) * 64;
  const int n0 = nt * 128, m0 = mt * 128;
  const int rrow = lane >> 2;
  const int koff = ((lane & 3) ^ ((lane >> 3) & 3)) * 8;  // pre-swizzled source chunk
  const int r0 = w * 32;
  const int fr = lane & 15;
  const int qo = (((lane >> 4) ^ ((lane >> 1) & 3)) * 8); // swizzled read slot

  f32x4 acc[4][4];
#pragma unroll
  for (int i = 0; i < 4; ++i)
#pragma unroll
    for (int j = 0; j < 4; ++j) acc[i][j] = (f32x4)(0.0f);

  auto stage = [&](int k0, int buf) {
#pragma unroll
    for (int q = 0; q < 2; ++q) {
      const int row = r0 + q * 16 + rrow;
      const int lb = (r0 + q * 16) * 32;
      gl16(&fT[(size_t)(n0 + row) * C_ + k0 + koff], &As[buf][lb]);
      gl16(&Wc[(size_t)(m0 + row) * C_ + k0 + koff], &Bs[buf][lb]);
    }
  };

  stage(0, 0);
  __syncthreads();
  int cur = 0;
  for (int k0 = 0; k0 < C_; k0 += 32) {
    const int nxt = cur ^ 1;
    if (k0 + 32 < C_) stage(k0 + 32, nxt);
    f16x8 af[4], bf[4];
#pragma unroll
    for (int i = 0; i < 4; ++i) {
      af[i] = *(const f16x8*)&As[cur][(wm + 16 * i + fr) * 32 + qo];
      bf[i] = *(const f16x8*)&Bs[cur][(wn + 16 * i + fr) * 32 + qo];
    }
#pragma unroll
    for (int i = 0; i < 4; ++i)
#pragma unroll
      for (int j = 0; j < 4; ++j)
        acc[i][j] = __builtin_amdgcn_mfma_f32_16x16x32_f16(af[i], bf[j], acc[i][j], 0, 0, 0);
    __syncthreads();
    cur = nxt;
  }
#pragma unroll
  for (int i = 0; i < 4; ++i) {
    const int nb = n0 + wm + 16 * i + ((lane >> 4) * 4);
#pragma unroll
    for (int j = 0; j < 4; ++j) {
      const int m = m0 + wn + 16 * j + (lane & 15);
#pragma unroll
      for (int r = 0; r < 4; ++r)
        f12[(size_t)(nb + r) * M_ + m] = (f16)acc[i][j][r];
    }
  }
}

// ---------------------------------------------------------------------------
// K2: logits[b][i][j] = sum_m f12[b*576+i][m] * f12[b*576+j][m+256].
// K=256. 2-phase prefetch + XOR swizzle. Grid (5 jt, 5 it, 32 b).
// ---------------------------------------------------------------------------
__global__ __launch_bounds__(256) void k_logits(
    const f16* __restrict__ f12, float* __restrict__ logits) {
  const int jt = blockIdx.x;
  const int it = blockIdx.y;
  const int b  = blockIdx.z;
  __shared__ __align__(16) f16 As[2][128 * 32], Bs[2][128 * 32];
  const int t = threadIdx.x, lane = t & 63, w = t >> 6;
  const int wm = (w >> 1) * 64, wn = (w & 1) * 64;
  const int i0 = it * 128, j0 = jt * 128;
  const int rrow = lane >> 2;
  const int koff = ((lane & 3) ^ ((lane >> 3) & 3)) * 8;
  const int r0 = w * 32;
  const int fr = lane & 15;
  const int qo = (((lane >> 4) ^ ((lane >> 1) & 3)) * 8);
  const f16* f_b = f12 + (size_t)b * N_ * M_;

  f32x4 acc[4][4];
#pragma unroll
  for (int i = 0; i < 4; ++i)
#pragma unroll
    for (int j = 0; j < 4; ++j) acc[i][j] = (f32x4)(0.0f);

  auto stage = [&](int k0, int buf) {
#pragma unroll
    for (int q = 0; q < 2; ++q) {
      const int row = r0 + q * 16 + rrow;
      const int ig = min(i0 + row, N_ - 1);
      const int jg = min(j0 + row, N_ - 1);
      const int lb = (r0 + q * 16) * 32;
      gl16(&f_b[(size_t)ig * M_ + k0 + koff], &As[buf][lb]);
      gl16(&f_b[(size_t)jg * M_ + MID_ + k0 + koff], &Bs[buf][lb]);
    }
  };

  stage(0, 0);
  __syncthreads();
  int cur = 0;
  for (int k0 = 0; k0 < MID_; k0 += 32) {
    const int nxt = cur ^ 1;
    if (k0 + 32 < MID_) stage(k0 + 32, nxt);
    f16x8 af[4], bf[4];
#pragma unroll
    for (int i = 0; i < 4; ++i) {
      af[i] = *(const f16x8*)&As[cur][(wm + 16 * i + fr) * 32 + qo];
      bf[i] = *(const f16x8*)&Bs[cur][(wn + 16 * i + fr) * 32 + qo];
    }
#pragma unroll
    for (int i = 0; i < 4; ++i)
#pragma unroll
      for (int j = 0; j < 4; ++j)
        acc[i][j] = __builtin_amdgcn_mfma_f32_16x16x32_f16(af[i], bf[j], acc[i][j], 0, 0, 0);
    __syncthreads();
    cur = nxt;
  }
  float* log_b = logits + (size_t)b * N_ * N_;
#pragma unroll
  for (int i = 0; i < 4; ++i) {
    const int ibase = i0 + wm + 16 * i + ((lane >> 4) * 4);
#pragma unroll
    for (int j = 0; j < 4; ++j) {
      const int jj = j0 + wn + 16 * j + (lane & 15);
      if (jj < N_) {
#pragma unroll
        for (int r = 0; r < 4; ++r) {
          const int ii = ibase + r;
          if (ii < N_) log_b[(size_t)ii * N_ + jj] = acc[i][j][r];
        }
      }
    }
  }
}

// ---------------------------------------------------------------------------
// K3: row softmax (576) — 4 rows per 256-thread block; fp32 in, fp16 out.
// ---------------------------------------------------------------------------
__global__ __launch_bounds__(256) void k_softmax(
    const float* __restrict__ logits, f16* __restrict__ attn) {
  const int row = blockIdx.x * 4 + (threadIdx.x >> 6);
  const int lane = threadIdx.x & 63;
  const float* p = logits + (size_t)row * N_;
  f16* o = attn + (size_t)row * N_;
  float v[9];
  float mx = -INFINITY;
#pragma unroll
  for (int q = 0; q < 9; ++q) {
    v[q] = p[lane + q * 64];
    mx = fmaxf(mx, v[q]);
  }
#pragma unroll
  for (int off = 32; off > 0; off >>= 1) mx = fmaxf(mx, __shfl_down(mx, off));
  mx = __shfl(mx, 0);
  float s = 0.f;
#pragma unroll
  for (int q = 0; q < 9; ++q) {
    v[q] = __expf(v[q] - mx);
    s += v[q];
  }
#pragma unroll
  for (int off = 32; off > 0; off >>= 1) s += __shfl_down(s, off);
  s = __shfl(s, 0);
  const float inv = 1.0f / s;
#pragma unroll
  for (int q = 0; q < 9; ++q) o[lane + q * 64] = (f16)(v[q] * inv);
}

// ---------------------------------------------------------------------------
// K4: out[b][c][i] = alpha * sum_j attn[b][i][j]*camh[b][c][j] + camh[b][c][i]
// 2-phase prefetch + XOR swizzle. Grid (16 ct, 5 it, 32 b).
// ---------------------------------------------------------------------------
__global__ __launch_bounds__(256) void k_out(
    const f16* __restrict__ camh, const f16* __restrict__ attn,
    const float* __restrict__ alpha_p, float* __restrict__ out) {
  const int ct = blockIdx.x;
  const int it = blockIdx.y;
  const int b  = blockIdx.z;
  __shared__ __align__(16) f16 As[2][128 * 32], Bs[2][128 * 32];
  const int t = threadIdx.x, lane = t & 63, w = t >> 6;
  const int wm = (w >> 1) * 64, wn = (w & 1) * 64;
  const int c0 = ct * 128, i0 = it * 128;
  const int rrow = lane >> 2;
  const int koff = ((lane & 3) ^ ((lane >> 3) & 3)) * 8;
  const int r0 = w * 32;
  const int fr = lane & 15;
  const int qo = (((lane >> 4) ^ ((lane >> 1) & 3)) * 8);
  const f16* camh_b = camh + (size_t)b * C_ * N_;
  const f16* attn_b = attn + (size_t)b * N_ * N_;

  f32x4 acc[4][4];
#pragma unroll
  for (int i = 0; i < 4; ++i)
#pragma unroll
    for (int j = 0; j < 4; ++j) acc[i][j] = (f32x4)(0.0f);

  auto stage = [&](int k0, int buf) {
#pragma unroll
    for (int q = 0; q < 2; ++q) {
      const int row = r0 + q * 16 + rrow;
      const int cg = c0 + row;
      const int ig = min(i0 + row, N_ - 1);
      const int lb = (r0 + q * 16) * 32;
      gl16(&camh_b[(size_t)cg * N_ + k0 + koff], &As[buf][lb]);
      gl16(&attn_b[(size_t)ig * N_ + k0 + koff], &Bs[buf][lb]);
    }
  };

  stage(0, 0);
  __syncthreads();
  int cur = 0;
  for (int k0 = 0; k0 < N_; k0 += 32) {
    const int nxt = cur ^ 1;
    if (k0 + 32 < N_) stage(k0 + 32, nxt);
    f16x8 af[4], bf[4];
#pragma unroll
    for (int i = 0; i < 4; ++i) {
      af[i] = *(const f16x8*)&As[cur][(wm + 16 * i + fr) * 32 + qo];
      bf[i] = *(const f16x8*)&Bs[cur][(wn + 16 * i + fr) * 32 + qo];
    }
#pragma unroll
    for (int i = 0; i < 4; ++i)
#pragma unroll
      for (int j = 0; j < 4; ++j)
        acc[i][j] = __builtin_amdgcn_mfma_f32_16x16x32_f16(af[i], bf[j], acc[i][j], 0, 0, 0);
    __syncthreads();
    cur = nxt;
  }
  const float alpha = *alpha_p;
  float* out_b = out + (size_t)b * C_ * N_;
#pragma unroll
  for (int ii = 0; ii < 4; ++ii) {
    const int c = c0 + wm + 16 * ii + ((lane >> 4) * 4);
#pragma unroll
    for (int jj = 0; jj < 4; ++jj) {
      const int i = i0 + wn + 16 * jj + (lane & 15);
      if (i < N_) {
#pragma unroll
        for (int r = 0; r < 4; ++r) {
          const size_t off = (size_t)(c + r) * N_ + i;
          out_b[off] = alpha * acc[ii][jj][r] + (float)camh_b[off];
        }
      }
    }
  }
}

// ---------------------------------------------------------------------------
extern "C" void kernel_launch(void* const* d_in, const int* in_sizes, int n_in,
                              void* d_out, int out_size, void* d_ws,
                              size_t ws_size, hipStream_t stream) {
  const float* cam   = (const float*)d_in[0];
  const float* feat  = (const float*)d_in[1];
  const float* W1    = (const float*)d_in[2];
  const float* W2    = (const float*)d_in[3];
  const float* alpha = (const float*)d_in[4];
  float* out = (float*)d_out;

  // ws layout, 96.5 MB total:
  //  [0, 75.5M)      fT fp16  -> logits fp32 [0,42.5M) -> camh fp16 [0,75.5M)
  //  [75.5M, 94.4M)  f12 fp16 -> attn fp16 [75.5M, 86.1M)
  //  [94.4M, 96.5M)  Wcat fp16
  char* ws = (char*)d_ws;
  f16*   fT     = (f16*)ws;
  f16*   f12    = (f16*)(ws + 75497472);
  f16*   Wc     = (f16*)(ws + 94371840);
  float* logits = (float*)ws;             // over fT (dead after k_f12)
  f16*   attn   = (f16*)(ws + 75497472);  // over f12 (dead after k_logits)
  f16*   camh   = (f16*)ws;               // over logits (dead after k_softmax)

  k_prep_w<<<dim3(512), 256, 0, stream>>>(W1, W2, Wc);
  k_prep_feat<<<dim3(32, 9, B_), 256, 0, stream>>>(feat, fT);
  k_f12<<<dim3(4, 144), 256, 0, stream>>>(fT, Wc, f12);
  k_logits<<<dim3(5, 5, B_), 256, 0, stream>>>(f12, logits);
  k_softmax<<<dim3(NB_ / 4), 256, 0, stream>>>(logits, attn);
  k_prep_cam<<<dim3(18432), 256, 0, stream>>>(cam, camh);
  k_out<<<dim3(16, 5, B_), 256, 0, stream>>>(camh, attn, alpha, out);
}

// Round 2
// 541.776 us; speedup vs baseline: 1.0041x; 1.0041x over previous
//
#include <hip/hip_runtime.h>
#include <math.h>

typedef unsigned short u16;
typedef unsigned int u32;
typedef _Float16 f16;
typedef __attribute__((ext_vector_type(8))) _Float16 f16x8;   // MFMA A/B frag
typedef __attribute__((ext_vector_type(4))) float f32x4;      // MFMA acc

static constexpr int B_   = 32;
static constexpr int C_   = 2048;
static constexpr int N_   = 576;    // H*W
static constexpr int MID_ = 256;
static constexpr int M_   = 512;    // 2*MID
static constexpr int NB_  = B_ * N_;  // 18432 = 144*128

// global -> LDS direct DMA, 16 B per lane (wave-uniform LDS base + lane*16)
typedef const __attribute__((address_space(1))) unsigned int gu32_t;
typedef __attribute__((address_space(3))) unsigned int lu32_t;
__device__ __forceinline__ void gl16(const void* g, void* l) {
  __builtin_amdgcn_global_load_lds((gu32_t*)g, (lu32_t*)l, 16, 0, 0);
}

// LDS swizzle (rule #21: linear DMA dest + pre-swizzled global SOURCE + swizzled READ):
//   LDS tile row = 64 B = 4 slots of 16 B. slot s of row r holds global chunk
//   s ^ ((r>>1)&3). Staging lane l (dest = base + l*16) fetches global chunk
//   (l&3) ^ ((l>>3)&3) of row r0 + (l>>2). Fragment read slot is lane-constant:
//   qo = ((lane>>4) ^ ((lane>>1)&3)) * 8.
//   Proven round 1: SQ_LDS_BANK_CONFLICT 5.9M -> 0. The explicit double-buffer
//   tried alongside it REGRESSED (k_out 98->115 us, barrier vmcnt(0) drain
//   defeats the prefetch; m99/m100 lesson) -> reverted to single-buffer here.

// ---------------------------------------------------------------------------
// Prep W: Wcat = [W1;W2] (512x2048) -> fp16, k-contiguous.
// ---------------------------------------------------------------------------
__global__ __launch_bounds__(256) void k_prep_w(
    const float* __restrict__ W1, const float* __restrict__ W2,
    f16* __restrict__ Wc) {
  const int e0 = (blockIdx.x * 256 + threadIdx.x) * 8;
  const int m = e0 >> 11;
  const int c = e0 & 2047;
  const float* src = (m < MID_) ? &W1[(size_t)m * C_ + c]
                                : &W2[(size_t)(m - MID_) * C_ + c];
  const float4 a = *(const float4*)&src[0];
  const float4 b = *(const float4*)&src[4];
  f16x8 hv;
  hv[0] = (f16)a.x; hv[1] = (f16)a.y; hv[2] = (f16)a.z; hv[3] = (f16)a.w;
  hv[4] = (f16)b.x; hv[5] = (f16)b.y; hv[6] = (f16)b.z; hv[7] = (f16)b.w;
  *(f16x8*)&Wc[e0] = hv;
}

// ---------------------------------------------------------------------------
// Prep feat: feat[b][c][n] fp32 -> fT[(b*576+n)][c] fp16 (transpose).
// 64x64 tile via LDS; grid (32 ctiles, 9 ntiles, 32 b).
// ---------------------------------------------------------------------------
__global__ __launch_bounds__(256) void k_prep_feat(
    const float* __restrict__ feat, f16* __restrict__ fT) {
  const int c0 = blockIdx.x * 64;
  const int n0 = blockIdx.y * 64;
  const int b  = blockIdx.z;
  __shared__ float Ts[64][65];
  const float* src = feat + ((size_t)b * C_ + c0) * N_ + n0;
  const int t = threadIdx.x;
  const int tr  = t >> 4;
  const int tc4 = (t & 15) * 4;
#pragma unroll
  for (int e = 0; e < 4; ++e) {
    const int c = tr + e * 16;
    const float4 v = *(const float4*)&src[(size_t)c * N_ + tc4];
    Ts[c][tc4] = v.x; Ts[c][tc4 + 1] = v.y;
    Ts[c][tc4 + 2] = v.z; Ts[c][tc4 + 3] = v.w;
  }
  __syncthreads();
  const int co = (t & 7) * 8;
#pragma unroll
  for (int p = 0; p < 2; ++p) {
    const int n = (t >> 3) + p * 32;
    f16x8 hv;
#pragma unroll
    for (int e = 0; e < 8; ++e) hv[e] = (f16)Ts[co + e][n];
    *(f16x8*)&fT[((size_t)b * N_ + n0 + n) * C_ + c0 + co] = hv;
  }
}

// ---------------------------------------------------------------------------
// K1: f12[(b n)][m] = sum_c fT[(b n)][c] * Wcat[m][c]  — one flat GEMM,
// M=512, N=18432, K=2048. 128x128 tile, BK=32, fp16 MFMA.
// Single-buffer two-barrier + XOR swizzle. Grid (4 mtiles, 144 ntiles).
// ---------------------------------------------------------------------------
__global__ __launch_bounds__(256) void k_f12(
    const f16* __restrict__ fT, const f16* __restrict__ Wc,
    f16* __restrict__ f12) {
  const int mt = blockIdx.x;  // 0..3
  const int nt = blockIdx.y;  // 0..143
  __shared__ __align__(16) f16 As[128 * 32], Bs[128 * 32];
  const int t = threadIdx.x, lane = t & 63, w = t >> 6;
  const int wm = (w >> 1) * 64, wn = (w & 1) * 64;
  const int n0 = nt * 128, m0 = mt * 128;
  const int rrow = lane >> 2;
  const int koff = ((lane & 3) ^ ((lane >> 3) & 3)) * 8;  // pre-swizzled source chunk
  const int r0 = w * 32;
  const int fr = lane & 15;
  const int qo = (((lane >> 4) ^ ((lane >> 1) & 3)) * 8); // swizzled read slot

  f32x4 acc[4][4];
#pragma unroll
  for (int i = 0; i < 4; ++i)
#pragma unroll
    for (int j = 0; j < 4; ++j) acc[i][j] = (f32x4)(0.0f);

  for (int k0 = 0; k0 < C_; k0 += 32) {
#pragma unroll
    for (int q = 0; q < 2; ++q) {
      const int row = r0 + q * 16 + rrow;
      const int lb = (r0 + q * 16) * 32;
      gl16(&fT[(size_t)(n0 + row) * C_ + k0 + koff], &As[lb]);
      gl16(&Wc[(size_t)(m0 + row) * C_ + k0 + koff], &Bs[lb]);
    }
    __syncthreads();
    f16x8 af[4], bf[4];
#pragma unroll
    for (int i = 0; i < 4; ++i) {
      af[i] = *(const f16x8*)&As[(wm + 16 * i + fr) * 32 + qo];
      bf[i] = *(const f16x8*)&Bs[(wn + 16 * i + fr) * 32 + qo];
    }
#pragma unroll
    for (int i = 0; i < 4; ++i)
#pragma unroll
      for (int j = 0; j < 4; ++j)
        acc[i][j] = __builtin_amdgcn_mfma_f32_16x16x32_f16(af[i], bf[j], acc[i][j], 0, 0, 0);
    __syncthreads();
  }
#pragma unroll
  for (int i = 0; i < 4; ++i) {
    const int nb = n0 + wm + 16 * i + ((lane >> 4) * 4);
#pragma unroll
    for (int j = 0; j < 4; ++j) {
      const int m = m0 + wn + 16 * j + (lane & 15);
#pragma unroll
      for (int r = 0; r < 4; ++r)
        f12[(size_t)(nb + r) * M_ + m] = (f16)acc[i][j][r];
    }
  }
}

// ---------------------------------------------------------------------------
// K2: logits[b][i][j] = sum_m f12[b*576+i][m] * f12[b*576+j][m+256].
// K=256. Single-buffer two-barrier + XOR swizzle. Grid (5 jt, 5 it, 32 b).
// ---------------------------------------------------------------------------
__global__ __launch_bounds__(256) void k_logits(
    const f16* __restrict__ f12, float* __restrict__ logits) {
  const int jt = blockIdx.x;
  const int it = blockIdx.y;
  const int b  = blockIdx.z;
  __shared__ __align__(16) f16 As[128 * 32], Bs[128 * 32];
  const int t = threadIdx.x, lane = t & 63, w = t >> 6;
  const int wm = (w >> 1) * 64, wn = (w & 1) * 64;
  const int i0 = it * 128, j0 = jt * 128;
  const int rrow = lane >> 2;
  const int koff = ((lane & 3) ^ ((lane >> 3) & 3)) * 8;
  const int r0 = w * 32;
  const int fr = lane & 15;
  const int qo = (((lane >> 4) ^ ((lane >> 1) & 3)) * 8);
  const f16* f_b = f12 + (size_t)b * N_ * M_;

  f32x4 acc[4][4];
#pragma unroll
  for (int i = 0; i < 4; ++i)
#pragma unroll
    for (int j = 0; j < 4; ++j) acc[i][j] = (f32x4)(0.0f);

  for (int k0 = 0; k0 < MID_; k0 += 32) {
#pragma unroll
    for (int q = 0; q < 2; ++q) {
      const int row = r0 + q * 16 + rrow;
      const int ig = min(i0 + row, N_ - 1);
      const int jg = min(j0 + row, N_ - 1);
      const int lb = (r0 + q * 16) * 32;
      gl16(&f_b[(size_t)ig * M_ + k0 + koff], &As[lb]);
      gl16(&f_b[(size_t)jg * M_ + MID_ + k0 + koff], &Bs[lb]);
    }
    __syncthreads();
    f16x8 af[4], bf[4];
#pragma unroll
    for (int i = 0; i < 4; ++i) {
      af[i] = *(const f16x8*)&As[(wm + 16 * i + fr) * 32 + qo];
      bf[i] = *(const f16x8*)&Bs[(wn + 16 * i + fr) * 32 + qo];
    }
#pragma unroll
    for (int i = 0; i < 4; ++i)
#pragma unroll
      for (int j = 0; j < 4; ++j)
        acc[i][j] = __builtin_amdgcn_mfma_f32_16x16x32_f16(af[i], bf[j], acc[i][j], 0, 0, 0);
    __syncthreads();
  }
  float* log_b = logits + (size_t)b * N_ * N_;
#pragma unroll
  for (int i = 0; i < 4; ++i) {
    const int ibase = i0 + wm + 16 * i + ((lane >> 4) * 4);
#pragma unroll
    for (int j = 0; j < 4; ++j) {
      const int jj = j0 + wn + 16 * j + (lane & 15);
      if (jj < N_) {
#pragma unroll
        for (int r = 0; r < 4; ++r) {
          const int ii = ibase + r;
          if (ii < N_) log_b[(size_t)ii * N_ + jj] = acc[i][j][r];
        }
      }
    }
  }
}

// ---------------------------------------------------------------------------
// K3: row softmax (576) — 4 rows per 256-thread block; fp32 in, fp16 out.
// ---------------------------------------------------------------------------
__global__ __launch_bounds__(256) void k_softmax(
    const float* __restrict__ logits, f16* __restrict__ attn) {
  const int row = blockIdx.x * 4 + (threadIdx.x >> 6);
  const int lane = threadIdx.x & 63;
  const float* p = logits + (size_t)row * N_;
  f16* o = attn + (size_t)row * N_;
  float v[9];
  float mx = -INFINITY;
#pragma unroll
  for (int q = 0; q < 9; ++q) {
    v[q] = p[lane + q * 64];
    mx = fmaxf(mx, v[q]);
  }
#pragma unroll
  for (int off = 32; off > 0; off >>= 1) mx = fmaxf(mx, __shfl_down(mx, off));
  mx = __shfl(mx, 0);
  float s = 0.f;
#pragma unroll
  for (int q = 0; q < 9; ++q) {
    v[q] = __expf(v[q] - mx);
    s += v[q];
  }
#pragma unroll
  for (int off = 32; off > 0; off >>= 1) s += __shfl_down(s, off);
  s = __shfl(s, 0);
  const float inv = 1.0f / s;
#pragma unroll
  for (int q = 0; q < 9; ++q) o[lane + q * 64] = (f16)(v[q] * inv);
}

// ---------------------------------------------------------------------------
// K4 (fused prep_cam + out):
// out[b][c][i] = alpha * sum_j attn[b][i][j]*cam[b][c][j] + cam[b][c][i]
// A = cam fp32, reg-staged with in-flight fp32->fp16 convert (writes the SAME
// linear LDS bytes the DMA path used; source-chunk permutation keeps the
// swizzled read path unchanged). B = attn fp16 via global_load_lds.
// Residual add reads fp32 cam directly (more accurate than old fp16 round).
// Grid (16 ct, 5 it, 32 b).
// ---------------------------------------------------------------------------
__global__ __launch_bounds__(256) void k_out(
    const float* __restrict__ cam, const f16* __restrict__ attn,
    const float* __restrict__ alpha_p, float* __restrict__ out) {
  const int ct = blockIdx.x;
  const int it = blockIdx.y;
  const int b  = blockIdx.z;
  __shared__ __align__(16) f16 As[128 * 32], Bs[128 * 32];
  const int t = threadIdx.x, lane = t & 63, w = t >> 6;
  const int wm = (w >> 1) * 64, wn = (w & 1) * 64;
  const int c0 = ct * 128, i0 = it * 128;
  const int rrow = lane >> 2;
  const int koff = ((lane & 3) ^ ((lane >> 3) & 3)) * 8;
  const int r0 = w * 32;
  const int fr = lane & 15;
  const int qo = (((lane >> 4) ^ ((lane >> 1) & 3)) * 8);
  const float* cam_b = cam + (size_t)b * C_ * N_;
  const f16* attn_b = attn + (size_t)b * N_ * N_;

  f32x4 acc[4][4];
#pragma unroll
  for (int i = 0; i < 4; ++i)
#pragma unroll
    for (int j = 0; j < 4; ++j) acc[i][j] = (f32x4)(0.0f);

  for (int k0 = 0; k0 < N_; k0 += 32) {
    // Issue all global ops first (B DMA + A fp32 loads), then convert+write A.
    float4 a0[2], a1[2];
#pragma unroll
    for (int q = 0; q < 2; ++q) {
      const int row = r0 + q * 16 + rrow;
      const int ig = min(i0 + row, N_ - 1);
      const int lb = (r0 + q * 16) * 32;
      gl16(&attn_b[(size_t)ig * N_ + k0 + koff], &Bs[lb]);
      const float* s = &cam_b[(size_t)(c0 + row) * N_ + k0 + koff];
      a0[q] = *(const float4*)&s[0];
      a1[q] = *(const float4*)&s[4];
    }
#pragma unroll
    for (int q = 0; q < 2; ++q) {
      const int lb = (r0 + q * 16) * 32;
      f16x8 hv;
      hv[0] = (f16)a0[q].x; hv[1] = (f16)a0[q].y;
      hv[2] = (f16)a0[q].z; hv[3] = (f16)a0[q].w;
      hv[4] = (f16)a1[q].x; hv[5] = (f16)a1[q].y;
      hv[6] = (f16)a1[q].z; hv[7] = (f16)a1[q].w;
      *(f16x8*)&As[lb + lane * 8] = hv;
    }
    __syncthreads();
    f16x8 af[4], bf[4];
#pragma unroll
    for (int i = 0; i < 4; ++i) {
      af[i] = *(const f16x8*)&As[(wm + 16 * i + fr) * 32 + qo];
      bf[i] = *(const f16x8*)&Bs[(wn + 16 * i + fr) * 32 + qo];
    }
#pragma unroll
    for (int i = 0; i < 4; ++i)
#pragma unroll
      for (int j = 0; j < 4; ++j)
        acc[i][j] = __builtin_amdgcn_mfma_f32_16x16x32_f16(af[i], bf[j], acc[i][j], 0, 0, 0);
    __syncthreads();
  }
  const float alpha = *alpha_p;
  float* out_b = out + (size_t)b * C_ * N_;
#pragma unroll
  for (int ii = 0; ii < 4; ++ii) {
    const int c = c0 + wm + 16 * ii + ((lane >> 4) * 4);
#pragma unroll
    for (int jj = 0; jj < 4; ++jj) {
      const int i = i0 + wn + 16 * jj + (lane & 15);
      if (i < N_) {
#pragma unroll
        for (int r = 0; r < 4; ++r) {
          const size_t off = (size_t)(c + r) * N_ + i;
          out_b[off] = alpha * acc[ii][jj][r] + cam_b[off];
        }
      }
    }
  }
}

// ---------------------------------------------------------------------------
extern "C" void kernel_launch(void* const* d_in, const int* in_sizes, int n_in,
                              void* d_out, int out_size, void* d_ws,
                              size_t ws_size, hipStream_t stream) {
  const float* cam   = (const float*)d_in[0];
  const float* feat  = (const float*)d_in[1];
  const float* W1    = (const float*)d_in[2];
  const float* W2    = (const float*)d_in[3];
  const float* alpha = (const float*)d_in[4];
  float* out = (float*)d_out;

  // ws layout, 96.5 MB total:
  //  [0, 75.5M)      fT fp16  -> logits fp32 [0,42.5M)   (fT dead after k_f12)
  //  [75.5M, 94.4M)  f12 fp16 -> attn fp16 [75.5M, 86.1M) (f12 dead after k_logits)
  //  [94.4M, 96.5M)  Wcat fp16
  char* ws = (char*)d_ws;
  f16*   fT     = (f16*)ws;
  f16*   f12    = (f16*)(ws + 75497472);
  f16*   Wc     = (f16*)(ws + 94371840);
  float* logits = (float*)ws;             // over fT (dead after k_f12)
  f16*   attn   = (f16*)(ws + 75497472);  // over f12 (dead after k_logits)

  k_prep_w<<<dim3(512), 256, 0, stream>>>(W1, W2, Wc);
  k_prep_feat<<<dim3(32, 9, B_), 256, 0, stream>>>(feat, fT);
  k_f12<<<dim3(4, 144), 256, 0, stream>>>(fT, Wc, f12);
  k_logits<<<dim3(5, 5, B_), 256, 0, stream>>>(f12, logits);
  k_softmax<<<dim3(NB_ / 4), 256, 0, stream>>>(logits, attn);
  k_out<<<dim3(16, 5, B_), 256, 0, stream>>>(cam, attn, alpha, out);
}